// Round 1
// baseline (1191.823 us; speedup 1.0000x reference)
//
#include <hip/hip_runtime.h>
#include <math.h>

// Problem constants (B=8, Cin=Cout=64, H=W=64, 3x3 kernel pad 1)
#define NB     8
#define NC     64
#define HH     64
#define WW     64
#define HW     4096           // 64*64
#define KK     9
#define PLANE  2097152        // NB*NC*HW  (one [8,64,64,64] tensor)

// Workspace layout (float offsets)
#define WS_WT     0           // wT[8][576][64]          = 294912
#define WS_OWT    294912      // owT[8][576][27]         = 124416
#define WS_OB     419328      // obAll[8][27]            = 216
#define WS_OFFS   419544      // offs[8][8][27][4096]    = 7077888
#define WS_GATES  7497432     // gates[4][8][64][4096]   = 8388608
// total = 15886040 floats = 63.5 MB

struct Params {
    const float* x; const float* h; const float* c;
    const float* w[8]; const float* ow[8]; const float* ob[8];
    const float* bi; const float* bf; const float* bc; const float* bo;
    const float* wci; const float* wcf; const float* wco;
    float* out; float* ws;
};

__device__ __forceinline__ float sigf(float v) { return 1.f / (1.f + __expf(-v)); }

// ---------------------------------------------------------------------------
// K0: weight transposes into workspace
//   wT [br][(c*9+k)][o]  <- w_br [o][c][k]        (o-coalesced for GEMM)
//   owT[br][(c*9+t)][j]  <- ow_br[j][c][t]        (j-contiguous for s_load)
//   obAll[br][j]         <- ob_br[j]
// ---------------------------------------------------------------------------
__global__ __launch_bounds__(256) void k0_prep(Params p) {
    int i = blockIdx.x * 256 + threadIdx.x;
    float* ws = p.ws;
    if (i < 294912) {
        int br = i / 36864; int r = i % 36864;
        int ck = r >> 6;    int o = r & 63;
        int c = ck / 9;     int k = ck % 9;
        ws[WS_WT + i] = p.w[br][(o * 64 + c) * 9 + k];
    } else if (i < 294912 + 124416) {
        int ii = i - 294912;
        int br = ii / 15552; int r = ii % 15552;
        int ct = r / 27;     int j = r % 27;
        int c = ct / 9;      int t = ct % 9;
        ws[WS_OWT + ii] = p.ow[br][(j * 64 + c) * 9 + t];
    } else if (i < 294912 + 124416 + 216) {
        int ii = i - 419328;
        int br = ii / 27; int j = ii % 27;
        ws[WS_OB + ii] = p.ob[br][j];
    }
}

// ---------------------------------------------------------------------------
// K1: the 8 offset convs (plain 3x3, 64ch -> 27ch), fp32.
//   grid: 8 br * 8 b * 16 chunks = 1024 blocks of 256 (thread = pixel)
//   writes offs[br][b][27][4096]
// ---------------------------------------------------------------------------
__global__ __launch_bounds__(256) void k1_offconv(Params p) {
    int bid = blockIdx.x;
    int br = bid >> 7; int b = (bid >> 4) & 7; int chunk = bid & 15;
    int t = threadIdx.x;
    int px = chunk * 256 + t;          // flat pixel 0..4095
    int y = px >> 6, xx = px & 63;
    const float* inp = (br & 1) ? p.h : p.x;   // even branch (w1,w3,..) eats x
    const float* owT = p.ws + WS_OWT + br * 15552;
    const float* ob  = p.ws + WS_OB  + br * 27;

    float acc[27];
#pragma unroll
    for (int j = 0; j < 27; ++j) acc[j] = ob[j];

    for (int c = 0; c < 64; ++c) {
        const float* base = inp + ((size_t)(b * 64 + c) << 12);
        float v[9];
#pragma unroll
        for (int ki = 0; ki < 3; ++ki)
#pragma unroll
            for (int kj = 0; kj < 3; ++kj) {
                int yy = y + ki - 1, xz = xx + kj - 1;
                bool in = ((unsigned)yy < 64u) && ((unsigned)xz < 64u);
                v[ki * 3 + kj] = in ? base[yy * 64 + xz] : 0.f;
            }
        const float* wrow = owT + c * 9 * 27;
#pragma unroll
        for (int t9 = 0; t9 < 9; ++t9) {
            float vt = v[t9];
#pragma unroll
            for (int j = 0; j < 27; ++j) acc[j] += vt * wrow[t9 * 27 + j];
        }
    }
    float* outp = p.ws + WS_OFFS + (size_t)(br * 8 + b) * 27 * 4096;
#pragma unroll
    for (int j = 0; j < 27; ++j) outp[j * 4096 + px] = acc[j];
}

// ---------------------------------------------------------------------------
// K2: deformable sampling + weighted reduce for one gate.
//   grid: b(8) * row(64) * gate(4) = 2048 blocks of 256.
//   Per branch (2 per gate): coords->LDS, then 8 chunks of 8 channels:
//   gather S2[72][64] into LDS, GEMM with lane=pixel, wave o-set of 16
//   (weights wave-uniform -> SGPR). Gate pre-acts stored to ws.
// ---------------------------------------------------------------------------
__global__ __launch_bounds__(256, 4) void k2_deform(Params p) {
    __shared__ int4   sAddr[9][64];
    __shared__ float4 sW[9][64];
    __shared__ float  S2[72][65];

    int bid = blockIdx.x;
    int gate = bid & 3; int row = (bid >> 2) & 63; int b = bid >> 8;
    int t = threadIdx.x;
    int lane = t & 63;
    int o0 = __builtin_amdgcn_readfirstlane((t >> 6) * 16);

    const float* wT   = p.ws + WS_WT;
    const float* offs = p.ws + WS_OFFS;
    float* gp = p.ws + WS_GATES;

    float acc[16];
#pragma unroll
    for (int oo = 0; oo < 16; ++oo) acc[oo] = 0.f;

    for (int sub = 0; sub < 2; ++sub) {
        int br = gate * 2 + sub;
        const float* inp = sub ? p.h : p.x;
        const float* ofb = offs + (size_t)(br * 8 + b) * 27 * 4096 + row * 64;

        // Phase A: bilinear coords + (mask*inbound)-folded corner weights
        for (int i = t; i < 576; i += 256) {
            int px = i & 63; int k = i >> 6;
            float dy = ofb[(2 * k) * 4096 + px];
            float dx = ofb[(2 * k + 1) * 4096 + px];
            float mm = ofb[(18 + k) * 4096 + px];
            float m = sigf(mm);
            int ki = k / 3, kj = k % 3;
            float py  = (float)(row + ki - 1) + dy;
            float pxx = (float)(px + kj - 1) + dx;
            float y0f = floorf(py), x0f = floorf(pxx);
            float wy = py - y0f, wx = pxx - x0f;
            int y0 = (int)y0f, x0 = (int)x0f;
            float y0i = ((unsigned)y0 < 64u) ? 1.f : 0.f;
            float y1i = ((unsigned)(y0 + 1) < 64u) ? 1.f : 0.f;
            float x0i = ((unsigned)x0 < 64u) ? 1.f : 0.f;
            float x1i = ((unsigned)(x0 + 1) < 64u) ? 1.f : 0.f;
            float w00 = (1.f - wy) * (1.f - wx) * m * y0i * x0i;
            float w01 = (1.f - wy) * wx         * m * y0i * x1i;
            float w10 = wy         * (1.f - wx) * m * y1i * x0i;
            float w11 = wy         * wx         * m * y1i * x1i;
            int cy0 = min(max(y0, 0), 63),     cy1 = min(max(y0 + 1, 0), 63);
            int cx0 = min(max(x0, 0), 63),     cx1 = min(max(x0 + 1, 0), 63);
            sAddr[k][px] = make_int4(cy0 * 64 + cx0, cy0 * 64 + cx1,
                                     cy1 * 64 + cx0, cy1 * 64 + cx1);
            sW[k][px] = make_float4(w00, w01, w10, w11);
        }
        __syncthreads();

        for (int cc = 0; cc < 8; ++cc) {
            int c0 = cc * 8;
            // Phase B1: gather 8 channels x 9 taps x 64 px into S2[ck][px]
#pragma unroll
            for (int j = 0; j < 18; ++j) {
                int i = t + j * 256;
                int px = i & 63; int r = i >> 6;     // r = cl*9 + k = local ck
                int k = r % 9;   int cl = r / 9;
                const float* base = inp + ((size_t)(b * 64 + c0 + cl) << 12);
                int4   aa = sAddr[k][px];
                float4 wv = sW[k][px];
                float s = wv.x * base[aa.x] + wv.y * base[aa.y]
                        + wv.z * base[aa.z] + wv.w * base[aa.w];
                S2[r][px] = s;
            }
            __syncthreads();
            // Phase B2: GEMM  acc[o] += S2[ck][px] * wT[br][c0*9+ck][o]
            const float* wTb = wT + (size_t)br * 36864 + (size_t)c0 * 9 * 64 + o0;
            for (int ck = 0; ck < 72; ++ck) {
                float s = S2[ck][lane];
                const float* wp = wTb + ck * 64;
#pragma unroll
                for (int oo = 0; oo < 16; ++oo) acc[oo] += s * wp[oo];
            }
            __syncthreads();
        }
    }

    size_t gbase = ((size_t)(gate * 8 + b) * 64 + o0) * 4096 + row * 64 + lane;
#pragma unroll
    for (int oo = 0; oo < 16; ++oo) gp[gbase + (size_t)oo * 4096] = acc[oo];
}

// ---------------------------------------------------------------------------
// K3: pointwise ConvLSTM combine. grid: 2097152/256 = 8192 blocks.
// ---------------------------------------------------------------------------
__global__ __launch_bounds__(256) void k3_lstm(Params p) {
    int idx = blockIdx.x * 256 + threadIdx.x;      // [b][o][pixel] flat
    const float* gp = p.ws + WS_GATES;
    float gi = gp[idx];
    float gf = gp[idx + PLANE];
    float gc = gp[idx + 2 * PLANE];
    float go = gp[idx + 3 * PLANE];
    int o = (idx >> 12) & 63;
    float cold = p.c[idx];
    float ig = sigf(gi + cold * p.wci[o] + p.bi[o]);
    float fg = sigf(gf + cold * p.wcf[o] + p.bf[o]);
    float cn = fg * cold + ig * tanhf(gc + p.bc[o]);
    float og = sigf(go + cn * p.wco[o] + p.bo[o]);
    p.out[idx] = og * tanhf(cn);
    p.out[idx + PLANE] = cn;
}

// ---------------------------------------------------------------------------
extern "C" void kernel_launch(void* const* d_in, const int* in_sizes, int n_in,
                              void* d_out, int out_size, void* d_ws, size_t ws_size,
                              hipStream_t stream) {
    (void)in_sizes; (void)n_in; (void)out_size; (void)ws_size;
    Params P;
    P.x = (const float*)d_in[0];
    P.h = (const float*)d_in[1];
    P.c = (const float*)d_in[2];
    for (int i = 0; i < 8; ++i) {
        P.w[i]  = (const float*)d_in[3 + 3 * i];
        P.ow[i] = (const float*)d_in[4 + 3 * i];
        P.ob[i] = (const float*)d_in[5 + 3 * i];
    }
    P.bi  = (const float*)d_in[27];
    P.bf  = (const float*)d_in[28];
    P.bc  = (const float*)d_in[29];
    P.bo  = (const float*)d_in[30];
    P.wci = (const float*)d_in[31];
    P.wcf = (const float*)d_in[32];
    P.wco = (const float*)d_in[33];
    P.out = (float*)d_out;
    P.ws  = (float*)d_ws;

    k0_prep   <<<dim3(1639), dim3(256), 0, stream>>>(P);
    k1_offconv<<<dim3(1024), dim3(256), 0, stream>>>(P);
    k2_deform <<<dim3(2048), dim3(256), 0, stream>>>(P);
    k3_lstm   <<<dim3(8192), dim3(256), 0, stream>>>(P);
}

// Round 2
// 903.954 us; speedup vs baseline: 1.3185x; 1.3185x over previous
//
#include <hip/hip_runtime.h>
#include <math.h>

// Problem constants (B=8, Cin=Cout=64, H=W=64, 3x3 kernel pad 1)
#define NB     8
#define NC     64
#define HH     64
#define WW     64
#define HW     4096           // 64*64
#define KK     9
#define PLANE  2097152        // NB*NC*HW  (one [8,64,64,64] tensor)

// Workspace layout (float offsets)
#define WS_WT     0           // wT[8][576][64]          = 294912
#define WS_OWT    294912      // owT[8][576][27]         = 124416
#define WS_OB     419328      // obAll[8][27]            = 216
#define WS_OFFS   419544      // offs[8][8][27][4096]    = 7077888
#define WS_GATES  7497432     // gates[4][8][64][4096]   = 8388608
#define WS_XT     15886040    // xT[8][4096][64] (HWC)   = 2097152
#define WS_HT     17983192    // hT[8][4096][64] (HWC)   = 2097152
// total = 20080344 floats = 80.3 MB

struct Params {
    const float* x; const float* h; const float* c;
    const float* w[8]; const float* ow[8]; const float* ob[8];
    const float* bi; const float* bf; const float* bc; const float* bo;
    const float* wci; const float* wcf; const float* wco;
    float* out; float* ws;
};

__device__ __forceinline__ float sigf(float v) { return 1.f / (1.f + __expf(-v)); }

// ---------------------------------------------------------------------------
// K0: weight transposes into workspace
// ---------------------------------------------------------------------------
__global__ __launch_bounds__(256) void k0_prep(Params p) {
    int i = blockIdx.x * 256 + threadIdx.x;
    float* ws = p.ws;
    if (i < 294912) {
        int br = i / 36864; int r = i % 36864;
        int ck = r >> 6;    int o = r & 63;
        int c = ck / 9;     int k = ck % 9;
        ws[WS_WT + i] = p.w[br][(o * 64 + c) * 9 + k];
    } else if (i < 294912 + 124416) {
        int ii = i - 294912;
        int br = ii / 15552; int r = ii % 15552;
        int ct = r / 27;     int j = r % 27;
        int c = ct / 9;      int t = ct % 9;
        ws[WS_OWT + ii] = p.ow[br][(j * 64 + c) * 9 + t];
    } else if (i < 294912 + 124416 + 216) {
        int ii = i - 419328;
        int br = ii / 27; int j = ii % 27;
        ws[WS_OB + ii] = p.ob[br][j];
    }
}

// ---------------------------------------------------------------------------
// K0T: CHW -> HWC transpose of x and h into ws (LDS tile transpose).
//   grid: 2 tensors * 8 b * 64 rows = 1024 blocks of 256.
// ---------------------------------------------------------------------------
__global__ __launch_bounds__(256) void k0_transp(Params p) {
    __shared__ float tile[64][65];
    int bid = blockIdx.x;
    int row = bid & 63; int b = (bid >> 6) & 7; int ten = bid >> 9;
    const float* src = ten ? p.h : p.x;
    float* dst = p.ws + (ten ? WS_HT : WS_XT);
    int t = threadIdx.x; int lane = t & 63; int w4 = t >> 6;
#pragma unroll
    for (int i = 0; i < 16; ++i) {
        int c = i * 4 + w4;
        tile[c][lane] = src[((size_t)(b * 64 + c) << 12) + row * 64 + lane];
    }
    __syncthreads();
#pragma unroll
    for (int i = 0; i < 16; ++i) {
        int px = i * 4 + w4;
        dst[((size_t)(b * 4096 + row * 64 + px) << 6) + lane] = tile[lane][px];
    }
}

// ---------------------------------------------------------------------------
// K1: the 8 offset convs (plain 3x3, 64ch -> 27ch), fp32.  (unchanged)
// ---------------------------------------------------------------------------
__global__ __launch_bounds__(256) void k1_offconv(Params p) {
    int bid = blockIdx.x;
    int br = bid >> 7; int b = (bid >> 4) & 7; int chunk = bid & 15;
    int t = threadIdx.x;
    int px = chunk * 256 + t;          // flat pixel 0..4095
    int y = px >> 6, xx = px & 63;
    const float* inp = (br & 1) ? p.h : p.x;
    const float* owT = p.ws + WS_OWT + br * 15552;
    const float* ob  = p.ws + WS_OB  + br * 27;

    float acc[27];
#pragma unroll
    for (int j = 0; j < 27; ++j) acc[j] = ob[j];

    for (int c = 0; c < 64; ++c) {
        const float* base = inp + ((size_t)(b * 64 + c) << 12);
        float v[9];
#pragma unroll
        for (int ki = 0; ki < 3; ++ki)
#pragma unroll
            for (int kj = 0; kj < 3; ++kj) {
                int yy = y + ki - 1, xz = xx + kj - 1;
                bool in = ((unsigned)yy < 64u) && ((unsigned)xz < 64u);
                v[ki * 3 + kj] = in ? base[yy * 64 + xz] : 0.f;
            }
        const float* wrow = owT + c * 9 * 27;
#pragma unroll
        for (int t9 = 0; t9 < 9; ++t9) {
            float vt = v[t9];
#pragma unroll
            for (int j = 0; j < 27; ++j) acc[j] += vt * wrow[t9 * 27 + j];
        }
    }
    float* outp = p.ws + WS_OFFS + (size_t)(br * 8 + b) * 27 * 4096;
#pragma unroll
    for (int j = 0; j < 27; ++j) outp[j * 4096 + px] = acc[j];
}

// ---------------------------------------------------------------------------
// K2 v2: deformable sampling + weighted reduce, HWC coalesced gather.
//   grid: b(8) * row(64) * gate(4) = 2048 blocks of 256.
//   Per branch: Phase A coords->LDS (packed u16 addrs + fp32 corner wts),
//   then 4 chunks of 16 channels: 16-lane groups load 16 consecutive
//   channels at one sample point (= exactly one 64B line per corner),
//   S2[144][65] in LDS, then the SGPR-weight GEMM (lane=pixel, 16 o/wave).
// ---------------------------------------------------------------------------
__global__ __launch_bounds__(256, 3) void k2_deform(Params p) {
    __shared__ uint2  sA[9][64];     // packed corner addrs (4 x u16)
    __shared__ float4 sW[9][64];     // folded corner weights
    __shared__ float  S2[144][65];

    int bid = blockIdx.x;
    int gate = bid & 3; int row = (bid >> 2) & 63; int b = bid >> 8;
    int t = threadIdx.x;
    int lane = t & 63;
    int o0 = __builtin_amdgcn_readfirstlane((t >> 6) * 16);

    const float* wT   = p.ws + WS_WT;
    const float* offs = p.ws + WS_OFFS;
    float* gp = p.ws + WS_GATES;

    float acc[16];
#pragma unroll
    for (int oo = 0; oo < 16; ++oo) acc[oo] = 0.f;

    int cl = t & 15;      // channel within 16-chunk
    int pg = t >> 4;      // point-group 0..15

    for (int sub = 0; sub < 2; ++sub) {
        int br = gate * 2 + sub;
        const float* inT = p.ws + (sub ? WS_HT : WS_XT) + ((size_t)b << 18);
        const float* ofb = offs + (size_t)(br * 8 + b) * 27 * 4096 + row * 64;

        // Phase A: bilinear coords + (mask*inbound)-folded corner weights
        for (int i = t; i < 576; i += 256) {
            int px = i & 63; int k = i >> 6;
            float dy = ofb[(2 * k) * 4096 + px];
            float dx = ofb[(2 * k + 1) * 4096 + px];
            float mm = ofb[(18 + k) * 4096 + px];
            float m = sigf(mm);
            int ki = k / 3, kj = k % 3;
            float py  = (float)(row + ki - 1) + dy;
            float pxx = (float)(px + kj - 1) + dx;
            float y0f = floorf(py), x0f = floorf(pxx);
            float wy = py - y0f, wx = pxx - x0f;
            int y0 = (int)y0f, x0 = (int)x0f;
            float y0i = ((unsigned)y0 < 64u) ? 1.f : 0.f;
            float y1i = ((unsigned)(y0 + 1) < 64u) ? 1.f : 0.f;
            float x0i = ((unsigned)x0 < 64u) ? 1.f : 0.f;
            float x1i = ((unsigned)(x0 + 1) < 64u) ? 1.f : 0.f;
            float w00 = (1.f - wy) * (1.f - wx) * m * y0i * x0i;
            float w01 = (1.f - wy) * wx         * m * y0i * x1i;
            float w10 = wy         * (1.f - wx) * m * y1i * x0i;
            float w11 = wy         * wx         * m * y1i * x1i;
            int cy0 = min(max(y0, 0), 63),     cy1 = min(max(y0 + 1, 0), 63);
            int cx0 = min(max(x0, 0), 63),     cx1 = min(max(x0 + 1, 0), 63);
            sA[k][px] = make_uint2((unsigned)(cy0 * 64 + cx0) | ((unsigned)(cy0 * 64 + cx1) << 16),
                                   (unsigned)(cy1 * 64 + cx0) | ((unsigned)(cy1 * 64 + cx1) << 16));
            sW[k][px] = make_float4(w00, w01, w10, w11);
        }
        __syncthreads();

        for (int cc = 0; cc < 4; ++cc) {
            int c0 = cc * 16;
            const float* bp = inT + c0 + cl;
            // Phase B1: gather. 16 points per iteration, 16 channels each.
#pragma unroll 6
            for (int it = 0; it < 36; ++it) {
                int pnt = it * 16 + pg;          // 0..575
                int k = pnt >> 6; int px = pnt & 63;
                uint2 aa = sA[k][px];            // broadcast within 16-group
                float4 wv = sW[k][px];
                float v0 = bp[(size_t)(aa.x & 0xffffu) << 6];
                float v1 = bp[(size_t)(aa.x >> 16) << 6];
                float v2 = bp[(size_t)(aa.y & 0xffffu) << 6];
                float v3 = bp[(size_t)(aa.y >> 16) << 6];
                S2[cl * 9 + k][px] = wv.x * v0 + wv.y * v1 + wv.z * v2 + wv.w * v3;
            }
            __syncthreads();
            // Phase B2: GEMM  acc[o] += S2[r][px] * wT[br][c0*9+r][o]
            const float* wTb = wT + (size_t)br * 36864 + (size_t)c0 * 9 * 64 + o0;
            for (int r = 0; r < 144; ++r) {
                float s = S2[r][lane];
                const float* wp = wTb + r * 64;
#pragma unroll
                for (int oo = 0; oo < 16; ++oo) acc[oo] += s * wp[oo];
            }
            __syncthreads();
        }
    }

    size_t gbase = ((size_t)(gate * 8 + b) * 64 + o0) * 4096 + row * 64 + lane;
#pragma unroll
    for (int oo = 0; oo < 16; ++oo) gp[gbase + (size_t)oo * 4096] = acc[oo];
}

// ---------------------------------------------------------------------------
// K3: pointwise ConvLSTM combine. grid: 2097152/256 = 8192 blocks.
// ---------------------------------------------------------------------------
__global__ __launch_bounds__(256) void k3_lstm(Params p) {
    int idx = blockIdx.x * 256 + threadIdx.x;      // [b][o][pixel] flat
    const float* gp = p.ws + WS_GATES;
    float gi = gp[idx];
    float gf = gp[idx + PLANE];
    float gc = gp[idx + 2 * PLANE];
    float go = gp[idx + 3 * PLANE];
    int o = (idx >> 12) & 63;
    float cold = p.c[idx];
    float ig = sigf(gi + cold * p.wci[o] + p.bi[o]);
    float fg = sigf(gf + cold * p.wcf[o] + p.bf[o]);
    float cn = fg * cold + ig * tanhf(gc + p.bc[o]);
    float og = sigf(go + cn * p.wco[o] + p.bo[o]);
    p.out[idx] = og * tanhf(cn);
    p.out[idx + PLANE] = cn;
}

// ---------------------------------------------------------------------------
extern "C" void kernel_launch(void* const* d_in, const int* in_sizes, int n_in,
                              void* d_out, int out_size, void* d_ws, size_t ws_size,
                              hipStream_t stream) {
    (void)in_sizes; (void)n_in; (void)out_size; (void)ws_size;
    Params P;
    P.x = (const float*)d_in[0];
    P.h = (const float*)d_in[1];
    P.c = (const float*)d_in[2];
    for (int i = 0; i < 8; ++i) {
        P.w[i]  = (const float*)d_in[3 + 3 * i];
        P.ow[i] = (const float*)d_in[4 + 3 * i];
        P.ob[i] = (const float*)d_in[5 + 3 * i];
    }
    P.bi  = (const float*)d_in[27];
    P.bf  = (const float*)d_in[28];
    P.bc  = (const float*)d_in[29];
    P.bo  = (const float*)d_in[30];
    P.wci = (const float*)d_in[31];
    P.wcf = (const float*)d_in[32];
    P.wco = (const float*)d_in[33];
    P.out = (float*)d_out;
    P.ws  = (float*)d_ws;

    k0_prep   <<<dim3(1639), dim3(256), 0, stream>>>(P);
    k0_transp <<<dim3(1024), dim3(256), 0, stream>>>(P);
    k1_offconv<<<dim3(1024), dim3(256), 0, stream>>>(P);
    k2_deform <<<dim3(2048), dim3(256), 0, stream>>>(P);
    k3_lstm   <<<dim3(8192), dim3(256), 0, stream>>>(P);
}

// Round 3
// 382.776 us; speedup vs baseline: 3.1136x; 2.3616x over previous
//
#include <hip/hip_runtime.h>
#include <math.h>

// Problem constants (B=8, Cin=Cout=64, H=W=64, 3x3 kernel pad 1)
#define NB     8
#define NC     64
#define HW     4096           // 64*64
#define PLANE  2097152        // NB*NC*HW

// Workspace layout (float-slot offsets)
#define WS_WB     0           // bf16 wB[8][72][64][8]   (294912 bf16 = 147456 f)
#define WS_OWB    147456      // bf16 owB[8][72][32][8]  (147456 bf16 = 73728 f)
#define WS_OB     221184      // f32 obAll[8][27]
#define WS_OFFS   221400      // f32 offs[8][8][27][4096] = 7077888
#define WS_GATES  7299288     // f32 gates[4][8][64][4096] = 8388608
#define WS_XT     15687896    // bf16 xT[8][4096][64] HWC  (1048576 f)
#define WS_HT     16736472    // bf16 hT[8][4096][64] HWC  (1048576 f)
// total = 17785048 floats = 71.1 MB

typedef __bf16 bf16x8 __attribute__((ext_vector_type(8)));
typedef float  f32x4  __attribute__((ext_vector_type(4)));

struct Params {
    const float* x; const float* h; const float* c;
    const float* w[8]; const float* ow[8]; const float* ob[8];
    const float* bi; const float* bf; const float* bc; const float* bo;
    const float* wci; const float* wcf; const float* wco;
    float* out; float* ws;
};

__device__ __forceinline__ float sigf(float v) { return 1.f / (1.f + __expf(-v)); }
__device__ __forceinline__ unsigned short f2bf(float v) {
    __bf16 b = (__bf16)v;
    return __builtin_bit_cast(unsigned short, b);
}
__device__ __forceinline__ float bf2f(unsigned short u) {
    return (float)__builtin_bit_cast(__bf16, u);
}

// ---------------------------------------------------------------------------
// K0: pack weights into MFMA B-fragment layouts (bf16) + biases.
//   wB [br][kgrp][o(64)][j]  K-order: k = cc*288 + ktap*32 + cl, c=cc*32+cl
//   owB[br][kgrp][o(32)][j]  K-order: k = ktap*64 + c   (o>=27 zero-padded)
// ---------------------------------------------------------------------------
__global__ __launch_bounds__(256) void k0_prep(Params p) {
    int i = blockIdx.x * 256 + threadIdx.x;
    unsigned short* wb  = (unsigned short*)(p.ws + WS_WB);
    unsigned short* owb = (unsigned short*)(p.ws + WS_OWB);
    if (i < 294912) {
        int br = i / 36864; int r = i % 36864;
        int kgrp = r >> 9; int o = (r >> 3) & 63; int j = r & 7;
        int k = kgrp * 8 + j;
        int cc = k / 288; int r2 = k - cc * 288;
        int ktap = r2 >> 5; int cl = r2 & 31; int c = cc * 32 + cl;
        wb[i] = f2bf(p.w[br][(o * 64 + c) * 9 + ktap]);
    } else if (i < 294912 + 147456) {
        int ii = i - 294912;
        int br = ii / 18432; int r = ii % 18432;
        int kgrp = r >> 8; int o = (r >> 3) & 31; int j = r & 7;
        int k = kgrp * 8 + j;
        int ktap = k >> 6; int c = k & 63;
        float v = (o < 27) ? p.ow[br][(o * 64 + c) * 9 + ktap] : 0.f;
        owb[ii] = f2bf(v);
    } else if (i < 294912 + 147456 + 216) {
        int ii = i - 442368;
        int br = ii / 27; int j = ii % 27;
        p.ws[WS_OB + ii] = p.ob[br][j];
    }
}

// ---------------------------------------------------------------------------
// K0T: CHW fp32 -> HWC bf16 transpose of x and h.
//   grid: 2 tensors * 8 b * 64 rows = 1024 blocks of 256.
// ---------------------------------------------------------------------------
__global__ __launch_bounds__(256) void k0_transp(Params p) {
    __shared__ float tile[64][65];
    int bid = blockIdx.x;
    int row = bid & 63; int b = (bid >> 6) & 7; int ten = bid >> 9;
    const float* src = ten ? p.h : p.x;
    unsigned short* dst = (unsigned short*)(p.ws + (ten ? WS_HT : WS_XT));
    int t = threadIdx.x; int lane = t & 63; int w4 = t >> 6;
#pragma unroll
    for (int i = 0; i < 16; ++i) {
        int c = i * 4 + w4;
        tile[c][lane] = src[((size_t)(b * 64 + c) << 12) + row * 64 + lane];
    }
    __syncthreads();
#pragma unroll
    for (int i = 0; i < 16; ++i) {
        int px = i * 4 + w4;
        dst[((size_t)(b * 4096 + row * 64 + px) << 6) + lane] = f2bf(tile[lane][px]);
    }
}

// ---------------------------------------------------------------------------
// K1 v3: the 8 offset convs via MFMA (implicit GEMM, M=64px N=32(27) K=576).
//   grid: br(8) * b(8) * row(64) = 4096 blocks of 256.
//   Per dy-chunk (K=192 = 3 dx taps): stage A-tile from bf16 HWC input
//   (pure bit-copy), 6 K-steps x 2 o-tiles MFMA. Epilogue: LDS transpose,
//   + bias, coalesced CHW store to offs[br][b][27][4096].
// ---------------------------------------------------------------------------
__global__ __launch_bounds__(256) void k1_offconv(Params p) {
    __shared__ __align__(16) unsigned short A1[24 * 528];   // [kgrp][px 66][8] bf16
    __shared__ float LO[27 * 65];
    int bid = blockIdx.x;
    int row = bid & 63; int b = (bid >> 6) & 7; int br = bid >> 9;
    int t = threadIdx.x; int l = t & 63; int w = t >> 6;
    const unsigned short* inT =
        (const unsigned short*)(p.ws + ((br & 1) ? WS_HT : WS_XT)) + ((size_t)b << 18);
    const unsigned short* owb = (const unsigned short*)(p.ws + WS_OWB) + br * 18432;

    f32x4 acc0 = {0.f, 0.f, 0.f, 0.f};
    f32x4 acc1 = {0.f, 0.f, 0.f, 0.f};

    int c4 = (t & 15) * 4;
    for (int dy = 0; dy < 3; ++dy) {
        int srow = row + dy - 1;
        // stage A-tile: k_local = dx*64 + c
#pragma unroll
        for (int dx = 0; dx < 3; ++dx) {
#pragma unroll
            for (int i = 0; i < 4; ++i) {
                int px = i * 16 + (t >> 4);
                int spx = px + dx - 1;
                short4 v = {0, 0, 0, 0};
                if (((unsigned)srow < 64u) && ((unsigned)spx < 64u))
                    v = *(const short4*)(inT + (((size_t)srow * 64 + spx) << 6) + c4);
                *(short4*)(A1 + (dx * 8 + (c4 >> 3)) * 528 + px * 8 + (c4 & 7)) = v;
            }
        }
        __syncthreads();
        const unsigned short* obase = owb + dy * 24 * 256;
#pragma unroll
        for (int s = 0; s < 6; ++s) {
            bf16x8 af = *(const bf16x8*)(A1 + (s * 4 + (l >> 4)) * 528 + (w * 16 + (l & 15)) * 8);
            const unsigned short* bp = obase + (s * 4 + (l >> 4)) * 256 + (l & 15) * 8;
            bf16x8 b0 = *(const bf16x8*)(bp);
            bf16x8 b1 = *(const bf16x8*)(bp + 128);
            acc0 = __builtin_amdgcn_mfma_f32_16x16x32_bf16(af, b0, acc0, 0, 0, 0);
            acc1 = __builtin_amdgcn_mfma_f32_16x16x32_bf16(af, b1, acc1, 0, 0, 0);
        }
        __syncthreads();
    }
    // epilogue: D layout m=px=(l>>4)*4+r (+w*16), n=o=(l&15)
    {
        int oq = l & 15; int quad = l >> 4;
#pragma unroll
        for (int r = 0; r < 4; ++r) {
            LO[oq * 65 + w * 16 + quad * 4 + r] = acc0[r];
            int o2 = 16 + oq;
            if (o2 < 27) LO[o2 * 65 + w * 16 + quad * 4 + r] = acc1[r];
        }
    }
    __syncthreads();
    const float* obp = p.ws + WS_OB + br * 27;
    float* outp = p.ws + WS_OFFS + (size_t)((br * 8 + b) * 27) * 4096 + row * 64;
    for (int i = t; i < 27 * 64; i += 256) {
        int j = i >> 6; int px = i & 63;
        outp[(size_t)j * 4096 + px] = LO[j * 65 + px] + obp[j];
    }
}

// ---------------------------------------------------------------------------
// K2 v3: deformable sampling (HWC bf16 coalesced gather) + MFMA reduce.
//   grid: gate(4) * row(64) * b(8) = 2048 blocks of 256.
//   M=64 px, N=64 o (16/wave), K=1152 (2 subs x 2 cc-chunks x 288).
//   S staged in LDS in A-frag layout [kgrp][px(66)][8] bf16;
//   weights wB in B-frag layout from global (L2-resident).
// ---------------------------------------------------------------------------
__global__ __launch_bounds__(256) void k2_deform(Params p) {
    __shared__ uint2  sA[9][64];
    __shared__ float4 sW[9][64];
    __shared__ __align__(16) unsigned short arena[36 * 528];  // 38016 B; aliased by epilogue
    unsigned short* S2a = arena;
    float* LO = (float*)arena;              // [64][65] f32 = 16640 B

    int bid = blockIdx.x;
    int gate = bid & 3; int row = (bid >> 2) & 63; int b = bid >> 8;
    int t = threadIdx.x; int l = t & 63; int w = t >> 6;
    int o0 = w * 16;
    int cl = t & 31; int pg = t >> 5;

    const unsigned short* wBp = (const unsigned short*)(p.ws + WS_WB);
    const float* offs = p.ws + WS_OFFS;

    f32x4 acc[4];
#pragma unroll
    for (int pt = 0; pt < 4; ++pt) acc[pt] = (f32x4){0.f, 0.f, 0.f, 0.f};

    for (int sub = 0; sub < 2; ++sub) {
        int br = gate * 2 + sub;
        const unsigned short* inT =
            (const unsigned short*)(p.ws + (sub ? WS_HT : WS_XT)) + ((size_t)b << 18);
        const float* ofb = offs + (size_t)((br * 8 + b) * 27) * 4096 + row * 64;

        // Phase A: bilinear coords + (mask*inbound)-folded corner weights
        for (int i = t; i < 576; i += 256) {
            int px = i & 63; int k = i >> 6;
            float dy = ofb[(size_t)(2 * k) * 4096 + px];
            float dx = ofb[(size_t)(2 * k + 1) * 4096 + px];
            float mm = ofb[(size_t)(18 + k) * 4096 + px];
            float m = sigf(mm);
            int ki = k / 3, kj = k % 3;
            float py  = (float)(row + ki - 1) + dy;
            float pxx = (float)(px + kj - 1) + dx;
            float y0f = floorf(py), x0f = floorf(pxx);
            float wy = py - y0f, wx = pxx - x0f;
            int y0 = (int)y0f, x0 = (int)x0f;
            float y0i = ((unsigned)y0 < 64u) ? 1.f : 0.f;
            float y1i = ((unsigned)(y0 + 1) < 64u) ? 1.f : 0.f;
            float x0i = ((unsigned)x0 < 64u) ? 1.f : 0.f;
            float x1i = ((unsigned)(x0 + 1) < 64u) ? 1.f : 0.f;
            float w00 = (1.f - wy) * (1.f - wx) * m * y0i * x0i;
            float w01 = (1.f - wy) * wx         * m * y0i * x1i;
            float w10 = wy         * (1.f - wx) * m * y1i * x0i;
            float w11 = wy         * wx         * m * y1i * x1i;
            int cy0 = min(max(y0, 0), 63),     cy1 = min(max(y0 + 1, 0), 63);
            int cx0 = min(max(x0, 0), 63),     cx1 = min(max(x0 + 1, 0), 63);
            sA[k][px] = make_uint2((unsigned)(cy0 * 64 + cx0) | ((unsigned)(cy0 * 64 + cx1) << 16),
                                   (unsigned)(cy1 * 64 + cx0) | ((unsigned)(cy1 * 64 + cx1) << 16));
            sW[k][px] = make_float4(w00, w01, w10, w11);
        }
        __syncthreads();

        for (int cc = 0; cc < 2; ++cc) {
            const unsigned short* bp = inT + cc * 32 + cl;
            // B1: gather 576 points x 32 channels; k_local = ktap*32 + cl
#pragma unroll 4
            for (int it = 0; it < 72; ++it) {
                int pnt = it * 8 + pg;
                int ktap = pnt >> 6; int px = pnt & 63;
                uint2 aa = sA[ktap][px];
                float4 wv = sW[ktap][px];
                float v0 = bf2f(bp[(size_t)(aa.x & 0xffffu) << 6]);
                float v1 = bf2f(bp[(size_t)(aa.x >> 16) << 6]);
                float v2 = bf2f(bp[(size_t)(aa.y & 0xffffu) << 6]);
                float v3 = bf2f(bp[(size_t)(aa.y >> 16) << 6]);
                float s = wv.x * v0 + wv.y * v1 + wv.z * v2 + wv.w * v3;
                S2a[(ktap * 4 + (cl >> 3)) * 528 + px * 8 + (cl & 7)] = f2bf(s);
            }
            __syncthreads();
            // GEMM: 9 K-steps x 4 px-tiles
            int base = (br * 72 + cc * 36 + (l >> 4)) * 512 + (o0 + (l & 15)) * 8;
#pragma unroll
            for (int s = 0; s < 9; ++s) {
                bf16x8 bfg = *(const bf16x8*)(wBp + base + s * 2048);
                const unsigned short* ab = S2a + (s * 4 + (l >> 4)) * 528 + (l & 15) * 8;
#pragma unroll
                for (int pt = 0; pt < 4; ++pt) {
                    bf16x8 af = *(const bf16x8*)(ab + pt * 128);
                    acc[pt] = __builtin_amdgcn_mfma_f32_16x16x32_bf16(af, bfg, acc[pt], 0, 0, 0);
                }
            }
            __syncthreads();
        }
    }

    // epilogue: acc -> LDS transpose -> coalesced CHW store
    {
        int oq = l & 15; int quad = l >> 4;
#pragma unroll
        for (int pt = 0; pt < 4; ++pt)
#pragma unroll
            for (int r = 0; r < 4; ++r)
                LO[(o0 + oq) * 65 + pt * 16 + quad * 4 + r] = acc[pt][r];
    }
    __syncthreads();
    float* gp = p.ws + WS_GATES + (size_t)((gate * 8 + b) * 64) * 4096 + row * 64;
    for (int i = t; i < 4096; i += 256) {
        int o = i >> 6; int px = i & 63;
        gp[(size_t)o * 4096 + px] = LO[o * 65 + px];
    }
}

// ---------------------------------------------------------------------------
// K3: pointwise ConvLSTM combine. grid: 8192 blocks of 256.
// ---------------------------------------------------------------------------
__global__ __launch_bounds__(256) void k3_lstm(Params p) {
    int idx = blockIdx.x * 256 + threadIdx.x;      // [b][o][pixel] flat
    const float* gp = p.ws + WS_GATES;
    float gi = gp[idx];
    float gf = gp[idx + PLANE];
    float gc = gp[idx + 2 * PLANE];
    float go = gp[idx + 3 * PLANE];
    int o = (idx >> 12) & 63;
    float cold = p.c[idx];
    float ig = sigf(gi + cold * p.wci[o] + p.bi[o]);
    float fg = sigf(gf + cold * p.wcf[o] + p.bf[o]);
    float cn = fg * cold + ig * tanhf(gc + p.bc[o]);
    float og = sigf(go + cn * p.wco[o] + p.bo[o]);
    p.out[idx] = og * tanhf(cn);
    p.out[idx + PLANE] = cn;
}

// ---------------------------------------------------------------------------
extern "C" void kernel_launch(void* const* d_in, const int* in_sizes, int n_in,
                              void* d_out, int out_size, void* d_ws, size_t ws_size,
                              hipStream_t stream) {
    (void)in_sizes; (void)n_in; (void)out_size; (void)ws_size;
    Params P;
    P.x = (const float*)d_in[0];
    P.h = (const float*)d_in[1];
    P.c = (const float*)d_in[2];
    for (int i = 0; i < 8; ++i) {
        P.w[i]  = (const float*)d_in[3 + 3 * i];
        P.ow[i] = (const float*)d_in[4 + 3 * i];
        P.ob[i] = (const float*)d_in[5 + 3 * i];
    }
    P.bi  = (const float*)d_in[27];
    P.bf  = (const float*)d_in[28];
    P.bc  = (const float*)d_in[29];
    P.bo  = (const float*)d_in[30];
    P.wci = (const float*)d_in[31];
    P.wcf = (const float*)d_in[32];
    P.wco = (const float*)d_in[33];
    P.out = (float*)d_out;
    P.ws  = (float*)d_ws;

    k0_prep   <<<dim3(1729), dim3(256), 0, stream>>>(P);
    k0_transp <<<dim3(1024), dim3(256), 0, stream>>>(P);
    k1_offconv<<<dim3(4096), dim3(256), 0, stream>>>(P);
    k2_deform <<<dim3(2048), dim3(256), 0, stream>>>(P);
    k3_lstm   <<<dim3(8192), dim3(256), 0, stream>>>(P);
}

// Round 4
// 336.586 us; speedup vs baseline: 3.5409x; 1.1372x over previous
//
#include <hip/hip_runtime.h>
#include <math.h>

// Problem constants (B=8, Cin=Cout=64, H=W=64, 3x3 kernel pad 1)
#define NB     8
#define NC     64
#define HW     4096           // 64*64
#define PLANE  2097152        // NB*NC*HW

// Workspace layout (float-slot offsets)
#define WS_WB     0           // bf16 wB[8][72][64][8]   (294912 bf16 = 147456 f)
#define WS_OWB    147456      // bf16 owB[8][72][32][8]  (147456 bf16 = 73728 f)
#define WS_OB     221184      // f32 obAll[8][27]
#define WS_OFFS   221400      // f32 offs[8][8][27][4096] = 7077888
#define WS_GATES  7299288     // f32 gates[4][8][64][4096] = 8388608
#define WS_XT     15687896    // bf16 xT[8][4096][64] HWC  (1048576 f)
#define WS_HT     16736472    // bf16 hT[8][4096][64] HWC  (1048576 f)
// total = 17785048 floats = 71.1 MB

typedef __bf16 bf16x8 __attribute__((ext_vector_type(8)));
typedef float  f32x4  __attribute__((ext_vector_type(4)));

struct Params {
    const float* x; const float* h; const float* c;
    const float* w[8]; const float* ow[8]; const float* ob[8];
    const float* bi; const float* bf; const float* bc; const float* bo;
    const float* wci; const float* wcf; const float* wco;
    float* out; float* ws;
};

__device__ __forceinline__ float sigf(float v) { return 1.f / (1.f + __expf(-v)); }
__device__ __forceinline__ unsigned short f2bf(float v) {
    __bf16 b = (__bf16)v;
    return __builtin_bit_cast(unsigned short, b);
}
// bf16 pair unpack: lo/hi halves of a dword -> f32 (1 inst each)
__device__ __forceinline__ float blo(unsigned d) { return __builtin_bit_cast(float, d << 16); }
__device__ __forceinline__ float bhi(unsigned d) { return __builtin_bit_cast(float, d & 0xffff0000u); }

// ---------------------------------------------------------------------------
// K0: pack weights into MFMA B-fragment layouts (bf16) + biases.
//   Both tap-major K-order now: k = ktap*64 + c.
//   wB [br][kgrp][o(64)][j],  owB[br][kgrp][o(32)][j] (o>=27 zero-padded)
// ---------------------------------------------------------------------------
__global__ __launch_bounds__(256) void k0_prep(Params p) {
    int i = blockIdx.x * 256 + threadIdx.x;
    unsigned short* wb  = (unsigned short*)(p.ws + WS_WB);
    unsigned short* owb = (unsigned short*)(p.ws + WS_OWB);
    if (i < 294912) {
        int br = i / 36864; int r = i % 36864;
        int kgrp = r >> 9; int o = (r >> 3) & 63; int j = r & 7;
        int k = kgrp * 8 + j;
        int ktap = k >> 6; int c = k & 63;
        wb[i] = f2bf(p.w[br][(o * 64 + c) * 9 + ktap]);
    } else if (i < 294912 + 147456) {
        int ii = i - 294912;
        int br = ii / 18432; int r = ii % 18432;
        int kgrp = r >> 8; int o = (r >> 3) & 31; int j = r & 7;
        int k = kgrp * 8 + j;
        int ktap = k >> 6; int c = k & 63;
        float v = (o < 27) ? p.ow[br][(o * 64 + c) * 9 + ktap] : 0.f;
        owb[ii] = f2bf(v);
    } else if (i < 294912 + 147456 + 216) {
        int ii = i - 442368;
        int br = ii / 27; int j = ii % 27;
        p.ws[WS_OB + ii] = p.ob[br][j];
    }
}

// ---------------------------------------------------------------------------
// K0T: CHW fp32 -> HWC bf16 transpose of x and h.
// ---------------------------------------------------------------------------
__global__ __launch_bounds__(256) void k0_transp(Params p) {
    __shared__ float tile[64][65];
    int bid = blockIdx.x;
    int row = bid & 63; int b = (bid >> 6) & 7; int ten = bid >> 9;
    const float* src = ten ? p.h : p.x;
    unsigned short* dst = (unsigned short*)(p.ws + (ten ? WS_HT : WS_XT));
    int t = threadIdx.x; int lane = t & 63; int w4 = t >> 6;
#pragma unroll
    for (int i = 0; i < 16; ++i) {
        int c = i * 4 + w4;
        tile[c][lane] = src[((size_t)(b * 64 + c) << 12) + row * 64 + lane];
    }
    __syncthreads();
#pragma unroll
    for (int i = 0; i < 16; ++i) {
        int px = i * 4 + w4;
        dst[((size_t)(b * 4096 + row * 64 + px) << 6) + lane] = f2bf(tile[lane][px]);
    }
}

// ---------------------------------------------------------------------------
// K1 v4: offset convs, 4 branches per block (wave = branch).
//   grid: b(8) * row(64) * parity(2) = 1024 blocks of 256.
//   Per dy: stage one 66-px input row (HWC bf16) once; the 3 dx taps are
//   shifted LDS reads. Each wave: its branch, 4 px-tiles x 2 o-tiles MFMA.
// ---------------------------------------------------------------------------
__global__ __launch_bounds__(256) void k1_offconv(Params p) {
    __shared__ __align__(16) unsigned short rb[8 * 66 * 8];  // [cg][px+1][8]
    __shared__ float LO[32 * 66];
    int bid = blockIdx.x;
    int row = bid & 63; int b = (bid >> 6) & 7; int par = bid >> 9;
    int t = threadIdx.x; int l = t & 63; int w = t >> 6;
    int q = l >> 4; int n = l & 15;
    int br = par + 2 * w;
    const unsigned short* inT =
        (const unsigned short*)(p.ws + (par ? WS_HT : WS_XT)) + ((size_t)b << 18);
    const unsigned short* owb = (const unsigned short*)(p.ws + WS_OWB);

    f32x4 acc[4][2];
#pragma unroll
    for (int pt = 0; pt < 4; ++pt)
#pragma unroll
        for (int ot = 0; ot < 2; ++ot) acc[pt][ot] = (f32x4){0.f, 0.f, 0.f, 0.f};

    for (int dy = 0; dy < 3; ++dy) {
        int srow = row + dy - 1;
        __syncthreads();
#pragma unroll
        for (int i = 0; i < 3; ++i) {
            int unit = t + i * 256;
            if (unit < 528) {
                int pxi = unit >> 3; int cg = unit & 7;
                int spx = pxi - 1;
                uint4 v = {0u, 0u, 0u, 0u};
                if (((unsigned)srow < 64u) && ((unsigned)spx < 64u))
                    v = *(const uint4*)(inT + (((size_t)srow * 64 + spx) << 6) + cg * 8);
                *(uint4*)(rb + (cg * 66 + pxi) * 8) = v;
            }
        }
        __syncthreads();
#pragma unroll
        for (int s = 0; s < 6; ++s) {
            int dx = s >> 1;
            int cgb = (s & 1) * 4 + q;
            bf16x8 afs[4];
#pragma unroll
            for (int pt = 0; pt < 4; ++pt)
                afs[pt] = *(const bf16x8*)(rb + (cgb * 66 + pt * 16 + n + dx) * 8);
            int kb = (br * 72 + dy * 24 + s * 4 + q) * 32;
#pragma unroll
            for (int ot = 0; ot < 2; ++ot) {
                bf16x8 bfg = *(const bf16x8*)(owb + (size_t)(kb + ot * 16 + n) * 8);
#pragma unroll
                for (int pt = 0; pt < 4; ++pt)
                    acc[pt][ot] = __builtin_amdgcn_mfma_f32_16x16x32_bf16(afs[pt], bfg, acc[pt][ot], 0, 0, 0);
            }
        }
    }
    // epilogue: one branch at a time through LO
    for (int wr = 0; wr < 4; ++wr) {
        if (w == wr) {
#pragma unroll
            for (int pt = 0; pt < 4; ++pt)
#pragma unroll
                for (int ot = 0; ot < 2; ++ot)
#pragma unroll
                    for (int r = 0; r < 4; ++r)
                        LO[(ot * 16 + n) * 66 + pt * 16 + q * 4 + r] = acc[pt][ot][r];
        }
        __syncthreads();
        int brx = par + 2 * wr;
        const float* obp = p.ws + WS_OB + brx * 27;
        float* outp = p.ws + WS_OFFS + (size_t)((brx * 8 + b) * 27) * 4096 + row * 64;
        for (int i = t; i < 1728; i += 256) {
            int j = i >> 6; int px = i & 63;
            outp[(size_t)j * 4096 + px] = LO[j * 66 + px] + obp[j];
        }
        __syncthreads();
    }
}

// ---------------------------------------------------------------------------
// K2 v4: deform gather DIRECTLY into A-fragments (no S2 LDS stage).
//   grid: gate(4) * row(64) * b(8) = 2048 blocks of 256. Wave = px-tile.
//   Per K-step (32 consecutive channels, tap-major): 4 corner uint4 loads
//   give a lane its 8-channel A-fragment; B-frags from L1/L2-resident wB.
// ---------------------------------------------------------------------------
__global__ __launch_bounds__(256, 4) void k2_deform(Params p) {
    __shared__ uint2  sA[9][64];
    __shared__ float4 sW[9][64];
    __shared__ float  LO[64 * 66];

    int bid = blockIdx.x;
    int gate = bid & 3; int row = (bid >> 2) & 63; int b = bid >> 8;
    int t = threadIdx.x; int l = t & 63; int w = t >> 6;
    int q = l >> 4; int n = l & 15;
    int pxl = w * 16 + n;

    const unsigned short* wBp = (const unsigned short*)(p.ws + WS_WB);
    const float* offs = p.ws + WS_OFFS;

    f32x4 acc[4];
#pragma unroll
    for (int ot = 0; ot < 4; ++ot) acc[ot] = (f32x4){0.f, 0.f, 0.f, 0.f};

    for (int sub = 0; sub < 2; ++sub) {
        int br = gate * 2 + sub;
        const unsigned short* inT =
            (const unsigned short*)(p.ws + (sub ? WS_HT : WS_XT)) + ((size_t)b << 18);
        const float* ofb = offs + (size_t)((br * 8 + b) * 27) * 4096 + row * 64;

        __syncthreads();   // protect sA/sW from previous sub's readers
        // Phase A: bilinear coords + (mask*inbound)-folded corner weights
        for (int i = t; i < 576; i += 256) {
            int px = i & 63; int k = i >> 6;
            float dy = ofb[(size_t)(2 * k) * 4096 + px];
            float dx = ofb[(size_t)(2 * k + 1) * 4096 + px];
            float mm = ofb[(size_t)(18 + k) * 4096 + px];
            float m = sigf(mm);
            int ki = k / 3, kj = k % 3;
            float py  = (float)(row + ki - 1) + dy;
            float pxx = (float)(px + kj - 1) + dx;
            float y0f = floorf(py), x0f = floorf(pxx);
            float wy = py - y0f, wx = pxx - x0f;
            int y0 = (int)y0f, x0 = (int)x0f;
            float y0i = ((unsigned)y0 < 64u) ? 1.f : 0.f;
            float y1i = ((unsigned)(y0 + 1) < 64u) ? 1.f : 0.f;
            float x0i = ((unsigned)x0 < 64u) ? 1.f : 0.f;
            float x1i = ((unsigned)(x0 + 1) < 64u) ? 1.f : 0.f;
            float w00 = (1.f - wy) * (1.f - wx) * m * y0i * x0i;
            float w01 = (1.f - wy) * wx         * m * y0i * x1i;
            float w10 = wy         * (1.f - wx) * m * y1i * x0i;
            float w11 = wy         * wx         * m * y1i * x1i;
            int cy0 = min(max(y0, 0), 63),     cy1 = min(max(y0 + 1, 0), 63);
            int cx0 = min(max(x0, 0), 63),     cx1 = min(max(x0 + 1, 0), 63);
            sA[k][px] = make_uint2((unsigned)(cy0 * 64 + cx0) | ((unsigned)(cy0 * 64 + cx1) << 16),
                                   (unsigned)(cy1 * 64 + cx0) | ((unsigned)(cy1 * 64 + cx1) << 16));
            sW[k][px] = make_float4(w00, w01, w10, w11);
        }
        __syncthreads();

        const unsigned short* cbase = inT + q * 8;
        for (int ktap = 0; ktap < 9; ++ktap) {
            uint2 aa = sA[ktap][pxl];
            float4 wv = sW[ktap][pxl];
            unsigned i0 = (aa.x & 0xffffu) << 6;
            unsigned i1 = (aa.x >> 16) << 6;
            unsigned i2 = (aa.y & 0xffffu) << 6;
            unsigned i3 = (aa.y >> 16) << 6;
#pragma unroll
            for (int half = 0; half < 2; ++half) {
                int s = ktap * 2 + half;
                const unsigned short* cb = cbase + half * 32;
                uint4 A0 = *(const uint4*)(cb + i0);
                uint4 A1 = *(const uint4*)(cb + i1);
                uint4 A2 = *(const uint4*)(cb + i2);
                uint4 A3 = *(const uint4*)(cb + i3);
                bf16x8 af;
#define COMB(m, d0, d1, d2, d3)                                                   \
                af[2*m]   = (__bf16)(wv.x*blo(d0) + wv.y*blo(d1) + wv.z*blo(d2) + wv.w*blo(d3)); \
                af[2*m+1] = (__bf16)(wv.x*bhi(d0) + wv.y*bhi(d1) + wv.z*bhi(d2) + wv.w*bhi(d3));
                COMB(0, A0.x, A1.x, A2.x, A3.x)
                COMB(1, A0.y, A1.y, A2.y, A3.y)
                COMB(2, A0.z, A1.z, A2.z, A3.z)
                COMB(3, A0.w, A1.w, A2.w, A3.w)
#undef COMB
                int kb = (br * 72 + s * 4 + q) * 64;
#pragma unroll
                for (int ot = 0; ot < 4; ++ot) {
                    bf16x8 bfg = *(const bf16x8*)(wBp + (size_t)(kb + ot * 16 + n) * 8);
                    acc[ot] = __builtin_amdgcn_mfma_f32_16x16x32_bf16(af, bfg, acc[ot], 0, 0, 0);
                }
            }
        }
    }

    // epilogue: acc -> LDS transpose -> coalesced CHW store
#pragma unroll
    for (int ot = 0; ot < 4; ++ot)
#pragma unroll
        for (int r = 0; r < 4; ++r)
            LO[(ot * 16 + n) * 66 + w * 16 + q * 4 + r] = acc[ot][r];
    __syncthreads();
    float* gp = p.ws + WS_GATES + (size_t)((gate * 8 + b) * 64) * 4096 + row * 64;
    for (int i = t; i < 4096; i += 256) {
        int o = i >> 6; int px = i & 63;
        gp[(size_t)o * 4096 + px] = LO[o * 66 + px];
    }
}

// ---------------------------------------------------------------------------
// K3: pointwise ConvLSTM combine. grid: 8192 blocks of 256.
// ---------------------------------------------------------------------------
__global__ __launch_bounds__(256) void k3_lstm(Params p) {
    int idx = blockIdx.x * 256 + threadIdx.x;      // [b][o][pixel] flat
    const float* gp = p.ws + WS_GATES;
    float gi = gp[idx];
    float gf = gp[idx + PLANE];
    float gc = gp[idx + 2 * PLANE];
    float go = gp[idx + 3 * PLANE];
    int o = (idx >> 12) & 63;
    float cold = p.c[idx];
    float ig = sigf(gi + cold * p.wci[o] + p.bi[o]);
    float fg = sigf(gf + cold * p.wcf[o] + p.bf[o]);
    float cn = fg * cold + ig * tanhf(gc + p.bc[o]);
    float og = sigf(go + cn * p.wco[o] + p.bo[o]);
    p.out[idx] = og * tanhf(cn);
    p.out[idx + PLANE] = cn;
}

// ---------------------------------------------------------------------------
extern "C" void kernel_launch(void* const* d_in, const int* in_sizes, int n_in,
                              void* d_out, int out_size, void* d_ws, size_t ws_size,
                              hipStream_t stream) {
    (void)in_sizes; (void)n_in; (void)out_size; (void)ws_size;
    Params P;
    P.x = (const float*)d_in[0];
    P.h = (const float*)d_in[1];
    P.c = (const float*)d_in[2];
    for (int i = 0; i < 8; ++i) {
        P.w[i]  = (const float*)d_in[3 + 3 * i];
        P.ow[i] = (const float*)d_in[4 + 3 * i];
        P.ob[i] = (const float*)d_in[5 + 3 * i];
    }
    P.bi  = (const float*)d_in[27];
    P.bf  = (const float*)d_in[28];
    P.bc  = (const float*)d_in[29];
    P.bo  = (const float*)d_in[30];
    P.wci = (const float*)d_in[31];
    P.wcf = (const float*)d_in[32];
    P.wco = (const float*)d_in[33];
    P.out = (float*)d_out;
    P.ws  = (float*)d_ws;

    k0_prep   <<<dim3(1729), dim3(256), 0, stream>>>(P);
    k0_transp <<<dim3(1024), dim3(256), 0, stream>>>(P);
    k1_offconv<<<dim3(1024), dim3(256), 0, stream>>>(P);
    k2_deform <<<dim3(2048), dim3(256), 0, stream>>>(P);
    k3_lstm   <<<dim3(8192), dim3(256), 0, stream>>>(P);
}